// Round 13
// baseline (618.151 us; speedup 1.0000x reference)
//
#include <hip/hip_runtime.h>
#include <math.h>

// Problem constants (N=2, C=64, H=96, W=96, PATCH=3)
static constexpr int NITEM = 2;
static constexpr int C = 64;
static constexpr int W = 96;
static constexpr int H = 96;
static constexpr int HW = H * W;        // 9216
static constexpr int HP = 94;           // H - 3 + 1
static constexpr int NP = HP * HP;      // 8836

// Dual-dy units: pair index s in [0,94): s even -> (dy = s, s+1); s odd ->
// (dy = -s, -(s+1)). |dy| ascending == center-out (small tail pieces).
// Units per item = sum_s ceil((94-s)/PL) = 600 at PL=8.
static constexpr int PL = 8;
static constexpr int UNITS_PER_N = 600;
static constexpr int NBLOCKS = 512;     // 2 blocks/CU x 256 CUs, 512 threads each

typedef float f32x2 __attribute__((ext_vector_type(2)));

// Packed fp32 FMA with per-element fma semantics (bit-identical to scalar fmaf
// chains). Compiler lowers <2 x float> llvm.fma to v_pk_fma_f32 on gfx950.
#if defined(__has_builtin) && __has_builtin(__builtin_elementwise_fma)
#define VFMA(q, a, b) (q) = __builtin_elementwise_fma((a), (b), (q))
#else
#define VFMA(q, a, b) do { (q).x = fmaf((a).x, (b).x, (q).x); \
                           (q).y = fmaf((a).y, (b).y, (q).y); } while (0)
#endif

// Order-preserving fp32 -> uint32 (v1 > v2  <=>  key(v1) > key(v2))
__device__ __forceinline__ unsigned int fkey(float v) {
    unsigned int u = __float_as_uint(v);
    return (u & 0x80000000u) ? ~u : (u | 0x80000000u);
}

// ---------------- Kernel 1: normalize + per-row panel repack ----------------
// fiP: per-row panel [n][row][c2][x] float2 (channel-pair; A-side b128 reads).
// frP: per-row panel [n][row][c][x] float scalar (B-side pixel-pair b64).
__global__ __launch_bounds__(256) void normalize_kernel(
    const float* __restrict__ f1, const float* __restrict__ f2,
    float2* __restrict__ fiP, float* __restrict__ frP, float* __restrict__ ssn)
{
    int t = blockIdx.x * 256 + threadIdx.x;
    const int perTensor = NITEM * HW;
    if (t >= 2 * perTensor) return;
    int which = t / perTensor;
    int p = t - which * perTensor;
    int n = p / HW;
    int pix = p - n * HW;
    const float* src = (which ? f2 : f1) + (size_t)n * C * HW + pix;
    float s = 0.f;
    #pragma unroll
    for (int c = 0; c < C; c++) {
        float v = src[c * HW];
        s = fmaf(v, v, s);
    }
    float norm = sqrtf(s);
    float scale = 1.0f / fmaxf(norm, 1e-12f);
    int y = pix / W, x = pix - y * W;
    if (which) {
        float* base = frP + ((size_t)n * H + y) * (C * W) + x;
        #pragma unroll
        for (int c = 0; c < C; c++)
            base[c * W] = src[c * HW] * scale;
        ssn[p] = s * scale * scale;
    } else {
        float2* base = fiP + ((size_t)n * H + y) * (32 * W) + x;
        #pragma unroll
        for (int c2 = 0; c2 < 32; c2++)
            base[c2 * W] = make_float2(src[(2 * c2) * HW] * scale,
                                       src[(2 * c2 + 1) * HW] * scale);
    }
}

// ---------------- Kernel 2: ref patch inverse norms ----------------
__global__ __launch_bounds__(256) void refnorm_kernel(
    const float* __restrict__ ssn, float* __restrict__ invn)
{
    int t = blockIdx.x * 256 + threadIdx.x;
    if (t >= NITEM * NP) return;
    int n = t / NP;
    int r = t - n * NP;
    int yr = r / HP, xr = r - yr * HP;
    const float* s = ssn + n * HW;
    float acc = 0.f;
    #pragma unroll
    for (int dy = 0; dy < 3; dy++)
        #pragma unroll
        for (int dx = 0; dx < 3; dx++)
            acc += s[(yr + dy) * W + (xr + dx)];
    invn[t] = 1.0f / (sqrtf(acc) + 1e-5f);
}

// ---- async unit staging: A row (24 KB) + B0 row (24 KB) + B1 row (24 KB) ----
// 72 chunks of 1024 B over 8 waves (9 chunks each); wave-uniform chunk routing.
__device__ __forceinline__ void stage_unit(const char* aRow, const char* b0Row,
                                           const char* b1Row, char* smA,
                                           char* smB0, char* smB1, int wv, int lane)
{
    #pragma unroll
    for (int c = 0; c < 9; ++c) {
        const int id = wv * 9 + c;          // 0..71, wave-uniform
        const char* g; char* d;
        if (id < 24)      { g = aRow  + (id << 10);        d = smA  + (id << 10); }
        else if (id < 48) { g = b0Row + ((id - 24) << 10); d = smB0 + ((id - 24) << 10); }
        else              { g = b1Row + ((id - 48) << 10); d = smB1 + ((id - 48) << 10); }
#if defined(__has_builtin) && __has_builtin(__builtin_amdgcn_global_load_lds)
        __builtin_amdgcn_global_load_lds(
            (const __attribute__((address_space(1))) unsigned int*)(const void*)(g + lane * 16),
            (__attribute__((address_space(3))) unsigned int*)(void*)d, 16, 0, 0);
#else
        *(float4*)(d + lane * 16) = *(const float4*)(g + lane * 16);
#endif
    }
}

// ---------------- Kernel 3: dual-dy fused row-pair GEMM + taps + argmax ----------
// 512 threads = two 256-thread halves; half h handles dy_h of the pair (d0, d1),
// SHARING the fi-row A panel (one A stage serves both GEMMs). Per-thread body is
// the verbatim R11 math (6x6 fragments, packed-FMA ascending-c chain, identical
// taps/finalize) -> bit-identical results. Half-1's one-row-narrower yi window is
// masked at finalize (wave-uniform); out-of-range fr rows are clamped and provably
// feed only masked outputs. LDS 78.5 KB + VGPR<=128 -> 2 blocks/CU (16 waves vs 12).
__global__ __launch_bounds__(512, 2) void corr_fused_kernel(
    const float2* __restrict__ fiP, const float* __restrict__ frP,
    const float* __restrict__ invn, unsigned long long* __restrict__ best,
    unsigned int* __restrict__ tick)
{
    __shared__ struct {
        f32x2 A[32][96];        // 24576 B: shared fi-row panel, channel-pair
        float B[2][64][96];     // 49152 B: per-half fr-row panels
        float sh[2][3][2][100]; //  4800 B: per-half halo rows
        int   sp;
    } sm;                       // ~78.5 KB -> 2 blocks/CU

    const int t = threadIdx.x;
    const int half = t >> 8;                // 0: dy=d0 (waves 0-3), 1: dy=d1 (4-7)
    const int tl = t & 255;
    const int tu = tl >> 4, tv = tl & 15;   // 16x16 grid of 6x6 fragments per half
    const int lane = t & 63;
    const int quad = tu & 3;
    const int wv = t >> 6;                  // 0..7
    const int u0 = 6 * tu, v0 = 6 * tv;
    const unsigned long long gmask = 0xFFFFull << (lane & 48);

    const int n = blockIdx.x & 1;           // 256 blocks per item

    const char* fiB = (const char*)(fiP + (size_t)n * H * (32 * W));  // 24576 B/row
    const char* frB = (const char*)(frP + (size_t)n * H * (C * W));   // 24576 B/row
    const float* inv = invn + (size_t)n * NP;
    unsigned long long* bn = best + (size_t)n * NP;

    float pA[6][6], pB[6][6];

    for (;;) {
        if (t == 0) sm.sp = (int)atomicAdd(&tick[n * 16], 1u);
        __syncthreads();
        const int uj = sm.sp;               // unit index within item
        if (uj >= UNITS_PER_N) break;

        // ---- decode unit -> (pair s, piece) ----
        int s = 0, ya = 0, nb = 0;
        {
            int r = uj;
            for (s = 0; s < 94; ++s) {
                int nyi0 = 94 - s;
                int q = (nyi0 + PL - 1) / PL;
                if (r < q) {
                    ya = ((s & 1) ? s : 0) + r * PL;
                    nb = nyi0 - r * PL; if (nb > PL) nb = PL;
                    break;
                }
                r -= q;
            }
        }
        const int sgn = (s & 1) ? -1 : 1;
        const int d0 = sgn * s;
        const int d1 = sgn * (s + 1);       // s=93 -> d1=-94: fully masked half
        const int dyh = half ? d1 : d0;
        const int yloH = half ? ((s & 1) ? s + 1 : 0) : ((s & 1) ? s : 0);
        const int yhiH = yloH + (half ? (93 - s) : (94 - s));
        const int yb = ya + nb;             // y runs ya..yb+1

        // prologue: stage A(ya) + B0 + B1 (fr rows clamped; garbage is masked)
        {
            int r0 = ya + d0; r0 = r0 < 0 ? 0 : (r0 > 95 ? 95 : r0);
            int r1 = ya + d1; r1 = r1 < 0 ? 0 : (r1 > 95 ? 95 : r1);
            stage_unit(fiB + (size_t)ya * 24576, frB + (size_t)r0 * 24576,
                       frB + (size_t)r1 * 24576, (char*)&sm.A[0][0],
                       (char*)&sm.B[0][0][0], (char*)&sm.B[1][0][0], wv, lane);
        }
        asm volatile("s_waitcnt vmcnt(0)" ::: "memory");
        __syncthreads();

        const float (*smB)[96] = sm.B[half];

        for (int y = ya; y <= yb + 1; ++y) {
            const bool doLd = (y <= yb);
            const int yi = y - 2;
            const bool doFin = (y >= ya + 2) && (yi >= yloH) && (yi < yhiH);
            const bool doA = (y > ya);
            const int yr = yi + dyh;        // in [0,94) whenever doFin

            // ---- GEMM: q[i][p] accumulates (acc[i][2p], acc[i][2p+1]) ----
            f32x2 q[6][3];
            #pragma unroll
            for (int i = 0; i < 6; ++i)
                #pragma unroll
                for (int p = 0; p < 3; ++p) q[i][p] = (f32x2)(0.f);

            #pragma unroll 2
            for (int c2 = 0; c2 < 32; ++c2) {
                const float4* ap = (const float4*)&sm.A[c2][u0];  // shared A
                float4 A0 = ap[0], A1 = ap[1], A2 = ap[2];
                const f32x2* bpe = (const f32x2*)&smB[2 * c2][v0];
                const f32x2* bpo = (const f32x2*)&smB[2 * c2 + 1][v0];
                f32x2 be0 = bpe[0], be1 = bpe[1], be2 = bpe[2];
                f32x2 bo0 = bpo[0], bo1 = bpo[1], bo2 = bpo[2];
                // even channel c = 2*c2 (first in ascending-c chain)
                f32x2 s0 = {A0.x, A0.x}, s1 = {A0.z, A0.z}, s2 = {A1.x, A1.x},
                      s3 = {A1.z, A1.z}, s4 = {A2.x, A2.x}, s5 = {A2.z, A2.z};
                VFMA(q[0][0], s0, be0); VFMA(q[0][1], s0, be1); VFMA(q[0][2], s0, be2);
                VFMA(q[1][0], s1, be0); VFMA(q[1][1], s1, be1); VFMA(q[1][2], s1, be2);
                VFMA(q[2][0], s2, be0); VFMA(q[2][1], s2, be1); VFMA(q[2][2], s2, be2);
                VFMA(q[3][0], s3, be0); VFMA(q[3][1], s3, be1); VFMA(q[3][2], s3, be2);
                VFMA(q[4][0], s4, be0); VFMA(q[4][1], s4, be1); VFMA(q[4][2], s4, be2);
                VFMA(q[5][0], s5, be0); VFMA(q[5][1], s5, be1); VFMA(q[5][2], s5, be2);
                // odd channel c = 2*c2+1 (second)
                f32x2 r0 = {A0.y, A0.y}, r1 = {A0.w, A0.w}, r2 = {A1.y, A1.y},
                      r3 = {A1.w, A1.w}, r4 = {A2.y, A2.y}, r5 = {A2.w, A2.w};
                VFMA(q[0][0], r0, bo0); VFMA(q[0][1], r0, bo1); VFMA(q[0][2], r0, bo2);
                VFMA(q[1][0], r1, bo0); VFMA(q[1][1], r1, bo1); VFMA(q[1][2], r1, bo2);
                VFMA(q[2][0], r2, bo0); VFMA(q[2][1], r2, bo1); VFMA(q[2][2], r2, bo2);
                VFMA(q[3][0], r3, bo0); VFMA(q[3][1], r3, bo1); VFMA(q[3][2], r3, bo2);
                VFMA(q[4][0], r4, bo0); VFMA(q[4][1], r4, bo1); VFMA(q[4][2], r4, bo2);
                VFMA(q[5][0], r5, bo0); VFMA(q[5][1], r5, bo1); VFMA(q[5][2], r5, bo2);
            }

            float acc[6][6];
            #pragma unroll
            for (int i = 0; i < 6; ++i)
                #pragma unroll
                for (int jj = 0; jj < 6; ++jj) acc[i][jj] = q[i][jj >> 1][jj & 1];

            // publish halo rows 0,1 for wave-boundary consumers (tu in {3,7,11})
            if (quad == 0 && tu >= 4) {
                const int g = (tu >> 2) - 1;
                #pragma unroll
                for (int jj = 0; jj < 6; ++jj) {
                    sm.sh[half][g][0][v0 + jj] = acc[0][jj];
                    sm.sh[half][g][1][v0 + jj] = acc[1][jj];
                }
            }
            __syncthreads();   // barrier1: panel reads done + halo visible

            // issue next-row DMA; latency hides under taps/finalize
            if (doLd) {
                int r0 = y + 1 + d0; r0 = r0 < 0 ? 0 : (r0 > 95 ? 95 : r0);
                int r1 = y + 1 + d1; r1 = r1 < 0 ? 0 : (r1 > 95 ? 95 : r1);
                stage_unit(fiB + (size_t)(y + 1) * 24576, frB + (size_t)r0 * 24576,
                           frB + (size_t)r1 * 24576, (char*)&sm.A[0][0],
                           (char*)&sm.B[0][0][0], (char*)&sm.B[1][0][0], wv, lane);
            }

            // ---- neighbor exchange (uniform shfls; select after) ----
            float c6[6], c7[6];
            #pragma unroll
            for (int i = 0; i < 6; ++i) {
                c6[i] = __shfl_down(acc[i][0], 1);   // col u0+i, v0+6
                c7[i] = __shfl_down(acc[i][1], 1);   // col u0+i, v0+7
            }
            float e6[8], e7[8];
            #pragma unroll
            for (int jj = 0; jj < 6; ++jj) {
                e6[jj] = __shfl_down(acc[0][jj], 16);  // row u0+6
                e7[jj] = __shfl_down(acc[1][jj], 16);  // row u0+7
            }
            e6[6] = __shfl_down(acc[0][0], 17);
            e6[7] = __shfl_down(acc[0][1], 17);
            e7[6] = __shfl_down(acc[1][0], 17);
            e7[7] = __shfl_down(acc[1][1], 17);
            if (quad == 3) {
                if (tu < 15) {
                    const int g = tu >> 2;
                    #pragma unroll
                    for (int jj = 0; jj < 8; ++jj) {
                        e6[jj] = sm.sh[half][g][0][v0 + jj];
                        e7[jj] = sm.sh[half][g][1][v0 + jj];
                    }
                } else {
                    #pragma unroll
                    for (int jj = 0; jj < 8; ++jj) { e6[jj] = 0.f; e7[jj] = 0.f; }
                }
            }

            float ivr[6];
            if (doFin) {
                const float* ivp = inv + (size_t)yr * HP;
                #pragma unroll
                for (int jj = 0; jj < 6; ++jj) {
                    int xr = v0 + jj;
                    ivr[jj] = ivp[xr > 93 ? 93 : xr];   // clamp; garbage masked later
                }
            }

            // ---- diagonal x-taps + y-rotation + finalize yi = y-2 ----
            #pragma unroll
            for (int i = 0; i < 6; ++i) {
                float bv = -INFINITY; int bxr = 0;
                #pragma unroll
                for (int jj = 0; jj < 6; ++jj) {
                    const int i1 = (i + 1 <= 5) ? i + 1 : 0;
                    const int j1 = (jj + 1 <= 5) ? jj + 1 : 0;
                    const int i2 = (i + 2 <= 5) ? i + 2 : 0;
                    const int j2 = (jj + 2 <= 5) ? jj + 2 : 0;
                    float E0 = acc[i][jj];
                    float E1 = (i + 1 <= 5)
                             ? ((jj + 1 <= 5) ? acc[i1][j1] : c6[i1])
                             : e6[jj + 1];
                    float E2 = (i + 2 <= 5)
                             ? ((jj + 2 <= 5) ? acc[i2][j2]
                                              : ((jj + 2 == 6) ? c6[i2] : c7[i2]))
                             : ((i + 2 == 6) ? e6[jj + 2] : e7[jj + 2]);
                    float bx = (E0 + E1) + E2;           // (g0+g1)+g2, as pass2
                    if (doFin) {
                        float v = (pA[i][jj] + bx) * ivr[jj];  // ((B0+B1)+B2)*inv
                        int xr = v0 + jj;
                        if (xr < HP && (u0 + i) < HP && v > bv) { bv = v; bxr = xr; }
                    }
                    if (doA) pA[i][jj] = pB[i][jj] + bx;
                    pB[i][jj] = bx;
                }
                if (doFin) {
                    float mx = bv;
                    #pragma unroll
                    for (int m = 1; m < 16; m <<= 1)
                        mx = fmaxf(mx, __shfl_xor(mx, m));   // 16-lane xr-group max
                    unsigned long long ball = __ballot(bv == mx) & gmask;
                    int srcl = __ffsll(ball) - 1;            // lowest lane = min xr
                    int wxr = __shfl(bxr, srcl);
                    if (tv == 0 && (u0 + i) < HP) {
                        unsigned long long key =
                            ((unsigned long long)fkey(mx) << 32)
                          | (unsigned int)(~(unsigned int)(yr * HP + wxr));
                        const size_t off = (size_t)yi * HP + (u0 + i);
                        if (key > bn[off]) atomicMax(&bn[off], key);  // monotone: stale-skip safe
                    }
                }
            }

            if (doLd) asm volatile("s_waitcnt vmcnt(0)" ::: "memory");
            __syncthreads();   // barrier2: next panels staged in all waves
        }
    }
}

// ---------------- Kernel 4: expand to 9 shifted copies, channel-interleaved ----------------
__global__ __launch_bounds__(256) void expand_best_kernel(
    const unsigned long long* __restrict__ best, float* __restrict__ out)
{
    int t = blockIdx.x * 256 + threadIdx.x;
    const int total = NITEM * 18 * HW;
    if (t >= total) return;
    int x = t % W;
    int y = (t / W) % H;
    int chn = (t / HW) % 18;
    int n = t / (18 * HW);
    int k = chn >> 1;
    int b = chn & 1;          // 0 -> flow_h, 1 -> flow_w
    int is = k / 3, js = k - is * 3;
    int ys = y - is, xs = x - js;
    float val = 0.f;
    if (ys >= 0 && ys < HP && xs >= 0 && xs < HP) {
        int i = ys * HP + xs;
        unsigned long long key = best[(size_t)n * NP + i];
        int idx = (int)(~(unsigned int)key);
        int yr = idx / HP, xr = idx - yr * HP;
        val = b ? (float)(xr - xs) : (float)(yr - ys);
    }
    out[t] = val;
}

// ---------------- Launch ----------------
extern "C" void kernel_launch(void* const* d_in, const int* in_sizes, int n_in,
                              void* d_out, int out_size, void* d_ws, size_t ws_size,
                              hipStream_t stream) {
    (void)in_sizes; (void)n_in; (void)out_size; (void)ws_size;
    const float* f1 = (const float*)d_in[0];
    const float* f2 = (const float*)d_in[1];

    float2* fiP = (float2*)d_ws;                            // 2*96*32*96 float2 = 4.7 MB
    float*  frP = (float*)(fiP + (size_t)NITEM * H * 32 * W);  // 4.7 MB
    float*  ssn = frP + (size_t)NITEM * H * C * W;
    float*  invn = ssn + (size_t)NITEM * HW;
    unsigned long long* best =
        (unsigned long long*)((((uintptr_t)(invn + (size_t)NITEM * NP)) + 63) & ~(uintptr_t)63);
    unsigned int* tick = (unsigned int*)(best + (size_t)NITEM * NP);  // 2 pools, 64B apart
    // total ~9.7 MB of workspace

    normalize_kernel<<<(2 * NITEM * HW + 255) / 256, 256, 0, stream>>>(f1, f2, fiP, frP, ssn);
    refnorm_kernel<<<(NITEM * NP + 255) / 256, 256, 0, stream>>>(ssn, invn);
    hipMemsetAsync(best, 0, (size_t)NITEM * NP * sizeof(unsigned long long) + 512, stream);
    corr_fused_kernel<<<NBLOCKS, 512, 0, stream>>>(fiP, frP, invn, best, tick);
    expand_best_kernel<<<(NITEM * 18 * HW + 255) / 256, 256, 0, stream>>>(best, (float*)d_out);
}

// Round 14
// 575.977 us; speedup vs baseline: 1.0732x; 1.0732x over previous
//
#include <hip/hip_runtime.h>
#include <math.h>

// Problem constants (N=2, C=64, H=96, W=96, PATCH=3)
static constexpr int NITEM = 2;
static constexpr int C = 64;
static constexpr int W = 96;
static constexpr int H = 96;
static constexpr int HW = H * W;        // 9216
static constexpr int HP = 94;           // H - 3 + 1
static constexpr int NP = HP * HP;      // 8836

// Work units: per (n, dy) split the valid yi-range into PL-row pieces.
static constexpr int PL = 8;
static constexpr int UNITS_PER_N = 1188;
static constexpr int NBLOCKS = 768;     // 3 blocks/CU x 256 CUs

typedef float f32x2 __attribute__((ext_vector_type(2)));

// Explicit packed fp32 FMA (VOP3P). src0 is a 64-bit pair; op_sel/op_sel_hi
// broadcast its LOW (PK_LO) or HIGH (PK_HI) 32-bit element to both result
// halves; src1/acc are elementwise. One instruction = 2 fp32 FMAs/lane.
// Per-accumulator chain order is preserved by the macro call order ->
// bit-identical to the scalar ascending-c fmaf chain of all passing rounds.
#define PK_LO(accv, av, bv) \
    asm("v_pk_fma_f32 %0, %1, %2, %0 op_sel:[0,0,0] op_sel_hi:[0,1,1]" \
        : "+v"(accv) : "v"(av), "v"(bv))
#define PK_HI(accv, av, bv) \
    asm("v_pk_fma_f32 %0, %1, %2, %0 op_sel:[1,0,0] op_sel_hi:[1,1,1]" \
        : "+v"(accv) : "v"(av), "v"(bv))

// Order-preserving fp32 -> uint32 (v1 > v2  <=>  key(v1) > key(v2))
__device__ __forceinline__ unsigned int fkey(float v) {
    unsigned int u = __float_as_uint(v);
    return (u & 0x80000000u) ? ~u : (u | 0x80000000u);
}

// ---------------- Kernel 1: normalize + per-row panel repack ----------------
// fiP: per-row panel [n][row][c2][x] float2 (channel-pair; A-side b128 reads,
//      pairs (even,odd) feed pk_fma op_sel broadcasts directly).
// frP: per-row panel [n][row][c][x] float scalar (B-side pixel-pair b64).
__global__ __launch_bounds__(256) void normalize_kernel(
    const float* __restrict__ f1, const float* __restrict__ f2,
    float2* __restrict__ fiP, float* __restrict__ frP, float* __restrict__ ssn)
{
    int t = blockIdx.x * 256 + threadIdx.x;
    const int perTensor = NITEM * HW;
    if (t >= 2 * perTensor) return;
    int which = t / perTensor;
    int p = t - which * perTensor;
    int n = p / HW;
    int pix = p - n * HW;
    const float* src = (which ? f2 : f1) + (size_t)n * C * HW + pix;
    float s = 0.f;
    #pragma unroll
    for (int c = 0; c < C; c++) {
        float v = src[c * HW];
        s = fmaf(v, v, s);
    }
    float norm = sqrtf(s);
    float scale = 1.0f / fmaxf(norm, 1e-12f);
    int y = pix / W, x = pix - y * W;
    if (which) {
        float* base = frP + ((size_t)n * H + y) * (C * W) + x;
        #pragma unroll
        for (int c = 0; c < C; c++)
            base[c * W] = src[c * HW] * scale;
        ssn[p] = s * scale * scale;
    } else {
        float2* base = fiP + ((size_t)n * H + y) * (32 * W) + x;
        #pragma unroll
        for (int c2 = 0; c2 < 32; c2++)
            base[c2 * W] = make_float2(src[(2 * c2) * HW] * scale,
                                       src[(2 * c2 + 1) * HW] * scale);
    }
}

// ---------------- Kernel 2: ref patch inverse norms ----------------
__global__ __launch_bounds__(256) void refnorm_kernel(
    const float* __restrict__ ssn, float* __restrict__ invn)
{
    int t = blockIdx.x * 256 + threadIdx.x;
    if (t >= NITEM * NP) return;
    int n = t / NP;
    int r = t - n * NP;
    int yr = r / HP, xr = r - yr * HP;
    const float* s = ssn + n * HW;
    float acc = 0.f;
    #pragma unroll
    for (int dy = 0; dy < 3; dy++)
        #pragma unroll
        for (int dx = 0; dx < 3; dx++)
            acc += s[(yr + dy) * W + (xr + dx)];
    invn[t] = 1.0f / (sqrtf(acc) + 1e-5f);
}

// ---- async row staging: linear 24576B panel image -> LDS (per-wave quarter) ----
__device__ __forceinline__ void stage_row(const void* gsrc, void* ldst, int lane, int wv)
{
#if defined(__has_builtin) && __has_builtin(__builtin_amdgcn_global_load_lds)
    const char* g = (const char*)gsrc;
    char* l = (char*)ldst;
    #pragma unroll
    for (int c = 0; c < 6; ++c) {
        const int off = wv * 6144 + c * 1024;
        __builtin_amdgcn_global_load_lds(
            (const __attribute__((address_space(1))) unsigned int*)(const void*)(g + off + lane * 16),
            (__attribute__((address_space(3))) unsigned int*)(void*)(l + off),
            16, 0, 0);
    }
#else
    const char* g = (const char*)gsrc;
    char* l = (char*)ldst;
    #pragma unroll
    for (int c = 0; c < 6; ++c) {
        const int off = wv * 6144 + c * 1024 + lane * 16;
        *(float4*)(l + off) = *(const float4*)(g + off);
    }
#endif
}

// ---------------- Kernel 3: fused row-pair GEMM + register diagonal taps + argmax ----
// R11 body/schedule (proven 567 us) with the GEMM inner loop emitted as explicit
// v_pk_fma_f32: per c2, A pairs p_i = (even(u0+i), odd(u0+i)) come straight from
// the b128 panel reads; 36 VOP3P instructions (18 PK_LO even-channel + 18 PK_HI
// odd-channel) replace ~90 scalar fma+mov. Per-accumulator order: even then odd
// per c2, c2 ascending == ascending-c chain -> bit-identical results.
__global__ __launch_bounds__(256, 2) void corr_fused_kernel(
    const float2* __restrict__ fiP, const float* __restrict__ frP,
    const float* __restrict__ invn, unsigned long long* __restrict__ best,
    unsigned int* __restrict__ tick)
{
    __shared__ struct {
        f32x2 A[32][96];        // 24576 B: fi-row panel, channel-pair float2
        float B[64][96];        // 24576 B: fr-row panel, channel-major scalar
        float sh[3][2][100];    //  2400 B: halo rows for wave-boundary groups
        int   sp;
    } sm;                       // ~51.6 KB -> 3 blocks/CU

    const int t = threadIdx.x;
    const int tu = t >> 4, tv = t & 15;     // 16x16 grid of 6x6 fragments
    const int lane = t & 63;
    const int quad = tu & 3;                // row-subgroup within wave
    const int wv = t >> 6;
    const int u0 = 6 * tu, v0 = 6 * tv;
    const unsigned long long gmask = 0xFFFFull << (lane & 48);

    const int n = blockIdx.x & 1;           // 384 blocks per item, XCD-interleaved

    const float2* fiPn = fiP + (size_t)n * H * (32 * W);
    const float* frPn = frP + (size_t)n * H * (C * W);
    const float* inv = invn + (size_t)n * NP;
    unsigned long long* bn = best + (size_t)n * NP;

    float pA[6][6], pB[6][6];

    for (;;) {
        if (t == 0) sm.sp = (int)atomicAdd(&tick[n * 16], 1u);
        __syncthreads();
        const int uj = sm.sp;               // unit index within item
        if (uj >= UNITS_PER_N) break;

        // ---- decode unit -> (dy, ya, nb), center-out dy order ----
        int dy = 0, ya = 0, nb = 0;
        {
            int r = uj;
            for (int s = 0; s < 187; ++s) {
                int ady = (s + 1) >> 1;          // 0,1,1,2,2,...,93,93
                int nyi = 94 - ady;
                int q = (nyi + PL - 1) / PL;
                if (r < q) {
                    dy = (s & 1) ? -ady : ady;
                    ya = (dy < 0 ? -dy : 0) + r * PL;
                    nb = nyi - r * PL; if (nb > PL) nb = PL;
                    break;
                }
                r -= q;
            }
        }
        const int yb = ya + nb;             // finalize yi in [ya, yb); y runs ya..yb+1

        // prologue: DMA rows (ya, ya+dy)
        stage_row(fiPn + (size_t)ya * (32 * W), &sm.A[0][0], lane, wv);
        stage_row(frPn + (size_t)(ya + dy) * (C * W), &sm.B[0][0], lane, wv);
        asm volatile("s_waitcnt vmcnt(0)" ::: "memory");
        __syncthreads();

        for (int y = ya; y <= yb + 1; ++y) {
            const bool doLd = (y <= yb);
            const bool doFin = (y >= ya + 2);
            const bool doA = (y > ya);
            const int yi = y - 2;
            const int yr = yi + dy;

            // ---- GEMM: q[i][p] accumulates (acc[i][2p], acc[i][2p+1]) ----
            f32x2 q[6][3];
            #pragma unroll
            for (int i = 0; i < 6; ++i)
                #pragma unroll
                for (int p = 0; p < 3; ++p) q[i][p] = (f32x2)(0.f);

            #pragma unroll 2
            for (int c2 = 0; c2 < 32; ++c2) {
                const f32x2* ap = (const f32x2*)&sm.A[c2][u0];   // pairs (even,odd)/pixel
                f32x2 p0 = ap[0], p1 = ap[1], p2 = ap[2],
                      p3 = ap[3], p4 = ap[4], p5 = ap[5];        // merged to b128 by cg
                const f32x2* bpe = (const f32x2*)&sm.B[2 * c2][v0];
                const f32x2* bpo = (const f32x2*)&sm.B[2 * c2 + 1][v0];
                f32x2 be0 = bpe[0], be1 = bpe[1], be2 = bpe[2];
                f32x2 bo0 = bpo[0], bo1 = bpo[1], bo2 = bpo[2];
                // even channel c = 2*c2 (first in ascending-c chain)
                PK_LO(q[0][0], p0, be0); PK_LO(q[0][1], p0, be1); PK_LO(q[0][2], p0, be2);
                PK_LO(q[1][0], p1, be0); PK_LO(q[1][1], p1, be1); PK_LO(q[1][2], p1, be2);
                PK_LO(q[2][0], p2, be0); PK_LO(q[2][1], p2, be1); PK_LO(q[2][2], p2, be2);
                PK_LO(q[3][0], p3, be0); PK_LO(q[3][1], p3, be1); PK_LO(q[3][2], p3, be2);
                PK_LO(q[4][0], p4, be0); PK_LO(q[4][1], p4, be1); PK_LO(q[4][2], p4, be2);
                PK_LO(q[5][0], p5, be0); PK_LO(q[5][1], p5, be1); PK_LO(q[5][2], p5, be2);
                // odd channel c = 2*c2+1 (second)
                PK_HI(q[0][0], p0, bo0); PK_HI(q[0][1], p0, bo1); PK_HI(q[0][2], p0, bo2);
                PK_HI(q[1][0], p1, bo0); PK_HI(q[1][1], p1, bo1); PK_HI(q[1][2], p1, bo2);
                PK_HI(q[2][0], p2, bo0); PK_HI(q[2][1], p2, bo1); PK_HI(q[2][2], p2, bo2);
                PK_HI(q[3][0], p3, bo0); PK_HI(q[3][1], p3, bo1); PK_HI(q[3][2], p3, bo2);
                PK_HI(q[4][0], p4, bo0); PK_HI(q[4][1], p4, bo1); PK_HI(q[4][2], p4, bo2);
                PK_HI(q[5][0], p5, bo0); PK_HI(q[5][1], p5, bo1); PK_HI(q[5][2], p5, bo2);
            }

            float acc[6][6];
            #pragma unroll
            for (int i = 0; i < 6; ++i)
                #pragma unroll
                for (int jj = 0; jj < 6; ++jj) acc[i][jj] = q[i][jj >> 1][jj & 1];

            // publish halo rows 0,1 for wave-boundary consumers (tu in {3,7,11})
            if (quad == 0 && tu >= 4) {
                const int g = (tu >> 2) - 1;
                #pragma unroll
                for (int jj = 0; jj < 6; ++jj) {
                    sm.sh[g][0][v0 + jj] = acc[0][jj];
                    sm.sh[g][1][v0 + jj] = acc[1][jj];
                }
            }
            __syncthreads();   // barrier1: panel reads done + halo visible

            // issue next-row DMA; latency hides under taps/finalize
            if (doLd) {
                stage_row(fiPn + (size_t)(y + 1) * (32 * W), &sm.A[0][0], lane, wv);
                stage_row(frPn + (size_t)(y + 1 + dy) * (C * W), &sm.B[0][0], lane, wv);
            }

            // ---- neighbor exchange (uniform shfls; select after) ----
            float c6[6], c7[6];
            #pragma unroll
            for (int i = 0; i < 6; ++i) {
                c6[i] = __shfl_down(acc[i][0], 1);   // col u0+i, v0+6
                c7[i] = __shfl_down(acc[i][1], 1);   // col u0+i, v0+7
            }
            float e6[8], e7[8];
            #pragma unroll
            for (int jj = 0; jj < 6; ++jj) {
                e6[jj] = __shfl_down(acc[0][jj], 16);  // row u0+6
                e7[jj] = __shfl_down(acc[1][jj], 16);  // row u0+7
            }
            e6[6] = __shfl_down(acc[0][0], 17);
            e6[7] = __shfl_down(acc[0][1], 17);
            e7[6] = __shfl_down(acc[1][0], 17);
            e7[7] = __shfl_down(acc[1][1], 17);
            if (quad == 3) {
                if (tu < 15) {
                    const int g = tu >> 2;
                    #pragma unroll
                    for (int jj = 0; jj < 8; ++jj) {
                        e6[jj] = sm.sh[g][0][v0 + jj];
                        e7[jj] = sm.sh[g][1][v0 + jj];
                    }
                } else {
                    #pragma unroll
                    for (int jj = 0; jj < 8; ++jj) { e6[jj] = 0.f; e7[jj] = 0.f; }
                }
            }

            float ivr[6];
            if (doFin) {
                const float* ivp = inv + (size_t)yr * HP;
                #pragma unroll
                for (int jj = 0; jj < 6; ++jj) {
                    int xr = v0 + jj;
                    ivr[jj] = ivp[xr > 93 ? 93 : xr];   // clamp; garbage masked later
                }
            }

            // ---- diagonal x-taps + y-rotation + finalize yi = y-2 ----
            #pragma unroll
            for (int i = 0; i < 6; ++i) {
                float bv = -INFINITY; int bxr = 0;
                #pragma unroll
                for (int jj = 0; jj < 6; ++jj) {
                    const int i1 = (i + 1 <= 5) ? i + 1 : 0;
                    const int j1 = (jj + 1 <= 5) ? jj + 1 : 0;
                    const int i2 = (i + 2 <= 5) ? i + 2 : 0;
                    const int j2 = (jj + 2 <= 5) ? jj + 2 : 0;
                    float E0 = acc[i][jj];
                    float E1 = (i + 1 <= 5)
                             ? ((jj + 1 <= 5) ? acc[i1][j1] : c6[i1])
                             : e6[jj + 1];
                    float E2 = (i + 2 <= 5)
                             ? ((jj + 2 <= 5) ? acc[i2][j2]
                                              : ((jj + 2 == 6) ? c6[i2] : c7[i2]))
                             : ((i + 2 == 6) ? e6[jj + 2] : e7[jj + 2]);
                    float bx = (E0 + E1) + E2;           // (g0+g1)+g2, as pass2
                    if (doFin) {
                        float v = (pA[i][jj] + bx) * ivr[jj];  // ((B0+B1)+B2)*inv
                        int xr = v0 + jj;
                        if (xr < HP && (u0 + i) < HP && v > bv) { bv = v; bxr = xr; }
                    }
                    if (doA) pA[i][jj] = pB[i][jj] + bx;
                    pB[i][jj] = bx;
                }
                if (doFin) {
                    float mx = bv;
                    #pragma unroll
                    for (int m = 1; m < 16; m <<= 1)
                        mx = fmaxf(mx, __shfl_xor(mx, m));   // 16-lane xr-group max
                    unsigned long long ball = __ballot(bv == mx) & gmask;
                    int srcl = __ffsll(ball) - 1;            // lowest lane = min xr
                    int wxr = __shfl(bxr, srcl);
                    if (tv == 0 && (u0 + i) < HP) {
                        unsigned long long key =
                            ((unsigned long long)fkey(mx) << 32)
                          | (unsigned int)(~(unsigned int)(yr * HP + wxr));
                        const size_t off = (size_t)yi * HP + (u0 + i);
                        if (key > bn[off]) atomicMax(&bn[off], key);  // monotone: stale-skip safe
                    }
                }
            }

            if (doLd) asm volatile("s_waitcnt vmcnt(0)" ::: "memory");
            __syncthreads();   // barrier2: next panels staged in all quarters
        }
    }
}

// ---------------- Kernel 4: expand to 9 shifted copies, channel-interleaved ----------------
__global__ __launch_bounds__(256) void expand_best_kernel(
    const unsigned long long* __restrict__ best, float* __restrict__ out)
{
    int t = blockIdx.x * 256 + threadIdx.x;
    const int total = NITEM * 18 * HW;
    if (t >= total) return;
    int x = t % W;
    int y = (t / W) % H;
    int chn = (t / HW) % 18;
    int n = t / (18 * HW);
    int k = chn >> 1;
    int b = chn & 1;          // 0 -> flow_h, 1 -> flow_w
    int is = k / 3, js = k - is * 3;
    int ys = y - is, xs = x - js;
    float val = 0.f;
    if (ys >= 0 && ys < HP && xs >= 0 && xs < HP) {
        int i = ys * HP + xs;
        unsigned long long key = best[(size_t)n * NP + i];
        int idx = (int)(~(unsigned int)key);
        int yr = idx / HP, xr = idx - yr * HP;
        val = b ? (float)(xr - xs) : (float)(yr - ys);
    }
    out[t] = val;
}

// ---------------- Launch ----------------
extern "C" void kernel_launch(void* const* d_in, const int* in_sizes, int n_in,
                              void* d_out, int out_size, void* d_ws, size_t ws_size,
                              hipStream_t stream) {
    (void)in_sizes; (void)n_in; (void)out_size; (void)ws_size;
    const float* f1 = (const float*)d_in[0];
    const float* f2 = (const float*)d_in[1];

    float2* fiP = (float2*)d_ws;                            // 2*96*32*96 float2 = 4.7 MB
    float*  frP = (float*)(fiP + (size_t)NITEM * H * 32 * W);  // 4.7 MB
    float*  ssn = frP + (size_t)NITEM * H * C * W;
    float*  invn = ssn + (size_t)NITEM * HW;
    unsigned long long* best =
        (unsigned long long*)((((uintptr_t)(invn + (size_t)NITEM * NP)) + 63) & ~(uintptr_t)63);
    unsigned int* tick = (unsigned int*)(best + (size_t)NITEM * NP);  // 2 pools, 64B apart
    // total ~9.7 MB of workspace

    normalize_kernel<<<(2 * NITEM * HW + 255) / 256, 256, 0, stream>>>(f1, f2, fiP, frP, ssn);
    refnorm_kernel<<<(NITEM * NP + 255) / 256, 256, 0, stream>>>(ssn, invn);
    hipMemsetAsync(best, 0, (size_t)NITEM * NP * sizeof(unsigned long long) + 512, stream);
    corr_fused_kernel<<<NBLOCKS, 256, 0, stream>>>(fiP, frP, invn, best, tick);
    expand_best_kernel<<<(NITEM * 18 * HW + 255) / 256, 256, 0, stream>>>(best, (float*)d_out);
}

// Round 15
// 560.611 us; speedup vs baseline: 1.1026x; 1.0274x over previous
//
#include <hip/hip_runtime.h>
#include <math.h>

// Problem constants (N=2, C=64, H=96, W=96, PATCH=3)
static constexpr int NITEM = 2;
static constexpr int C = 64;
static constexpr int W = 96;
static constexpr int H = 96;
static constexpr int HW = H * W;        // 9216
static constexpr int HP = 94;           // H - 3 + 1
static constexpr int NP = HP * HP;      // 8836

// Work units: per (n, dy) split the valid yi-range into PL-row pieces.
static constexpr int PL = 8;
static constexpr int UNITS_PER_N = 1188;
static constexpr int NBLOCKS = 768;     // 3 blocks/CU x 256 CUs

typedef float f32x2 __attribute__((ext_vector_type(2)));

// Packed fp32 FMA with per-element fma semantics (bit-identical to scalar fmaf
// chains). Compiler lowers <2 x float> llvm.fma to v_pk_fma_f32 on gfx950.
#if defined(__has_builtin) && __has_builtin(__builtin_elementwise_fma)
#define VFMA(q, a, b) (q) = __builtin_elementwise_fma((a), (b), (q))
#else
#define VFMA(q, a, b) do { (q).x = fmaf((a).x, (b).x, (q).x); \
                           (q).y = fmaf((a).y, (b).y, (q).y); } while (0)
#endif

// Order-preserving fp32 -> uint32 (v1 > v2  <=>  key(v1) > key(v2))
__device__ __forceinline__ unsigned int fkey(float v) {
    unsigned int u = __float_as_uint(v);
    return (u & 0x80000000u) ? ~u : (u | 0x80000000u);
}

// ---------------- Kernel 1: normalize + per-row panel repack ----------------
// fiP: per-row panel [n][row][c2][x] float2 (channel-pair interleaved -> A-side
//      fragments read as aligned ds_read_b128, 3 per 2 channels).
// frP: per-row panel [n][row][c][x] float scalar (B-side pixel-pair b64 for pk_fma).
// Both are linear 24576 B per row -> DMA-able via global_load_lds.
__global__ __launch_bounds__(256) void normalize_kernel(
    const float* __restrict__ f1, const float* __restrict__ f2,
    float2* __restrict__ fiP, float* __restrict__ frP, float* __restrict__ ssn)
{
    int t = blockIdx.x * 256 + threadIdx.x;
    const int perTensor = NITEM * HW;
    if (t >= 2 * perTensor) return;
    int which = t / perTensor;
    int p = t - which * perTensor;
    int n = p / HW;
    int pix = p - n * HW;
    const float* src = (which ? f2 : f1) + (size_t)n * C * HW + pix;
    float s = 0.f;
    #pragma unroll
    for (int c = 0; c < C; c++) {
        float v = src[c * HW];
        s = fmaf(v, v, s);
    }
    float norm = sqrtf(s);
    float scale = 1.0f / fmaxf(norm, 1e-12f);
    int y = pix / W, x = pix - y * W;
    if (which) {
        float* base = frP + ((size_t)n * H + y) * (C * W) + x;
        #pragma unroll
        for (int c = 0; c < C; c++)
            base[c * W] = src[c * HW] * scale;
        ssn[p] = s * scale * scale;
    } else {
        float2* base = fiP + ((size_t)n * H + y) * (32 * W) + x;
        #pragma unroll
        for (int c2 = 0; c2 < 32; c2++)
            base[c2 * W] = make_float2(src[(2 * c2) * HW] * scale,
                                       src[(2 * c2 + 1) * HW] * scale);
    }
}

// ---------------- Kernel 2: ref patch inverse norms ----------------
__global__ __launch_bounds__(256) void refnorm_kernel(
    const float* __restrict__ ssn, float* __restrict__ invn)
{
    int t = blockIdx.x * 256 + threadIdx.x;
    if (t >= NITEM * NP) return;
    int n = t / NP;
    int r = t - n * NP;
    int yr = r / HP, xr = r - yr * HP;
    const float* s = ssn + n * HW;
    float acc = 0.f;
    #pragma unroll
    for (int dy = 0; dy < 3; dy++)
        #pragma unroll
        for (int dx = 0; dx < 3; dx++)
            acc += s[(yr + dy) * W + (xr + dx)];
    invn[t] = 1.0f / (sqrtf(acc) + 1e-5f);
}

// ---- async row staging: linear 24576B panel image -> LDS (per-wave quarter) ----
__device__ __forceinline__ void stage_row(const void* gsrc, void* ldst, int lane, int wv)
{
#if defined(__has_builtin) && __has_builtin(__builtin_amdgcn_global_load_lds)
    const char* g = (const char*)gsrc;
    char* l = (char*)ldst;
    #pragma unroll
    for (int c = 0; c < 6; ++c) {
        const int off = wv * 6144 + c * 1024;
        __builtin_amdgcn_global_load_lds(
            (const __attribute__((address_space(1))) unsigned int*)(const void*)(g + off + lane * 16),
            (__attribute__((address_space(3))) unsigned int*)(void*)(l + off),
            16, 0, 0);
    }
#else
    const char* g = (const char*)gsrc;
    char* l = (char*)ldst;
    #pragma unroll
    for (int c = 0; c < 6; ++c) {
        const int off = wv * 6144 + c * 1024 + lane * 16;
        *(float4*)(l + off) = *(const float4*)(g + off);
    }
#endif
}

// ---------------- Kernel 3: fused row-pair GEMM + register diagonal taps + argmax ----
// Champion body (567 us, R9/R11): per (n, dy, yi-piece) stream pixel-rows y; the
// row-pair GEMM G_y[u][v] = dot(fi[y][u], fr[y+dy][v]) lives in 6x6 register
// fragments (16x16 thread grid), operands from single-buffered LDS panels staged
// by global_load_lds DMA; A reads are aligned b128 (channel-pair layout), B reads
// pixel-pair b64 feeding packed FMAs. Diagonal x-taps via shfl halo; y-taps via
// pA/pB register rotation; finalize: (pA+Bx)*inv, 16-lane argmax, read-guarded
// packed-u64 atomicMax. Association: even-then-odd per c2, c2 ascending ==
// ascending-c fmaf chain; (g0+g1)+g2 over dx; ((B0+B1)+B2)*inv over dy ->
// bit-identical to the original reference-checked kernels (absmax 0.0).
// Measured ceiling notes: VALU 52%, DS ~60%, occupancy 21.4 (3 blocks/CU);
// 7 structural variants (R7/R10/R12/R13/R14...) all null-or-worse. Register
// state ~110 floats: launch_bounds above (256,2) spills catastrophically (R6).
__global__ __launch_bounds__(256, 2) void corr_fused_kernel(
    const float2* __restrict__ fiP, const float* __restrict__ frP,
    const float* __restrict__ invn, unsigned long long* __restrict__ best,
    unsigned int* __restrict__ tick)
{
    __shared__ struct {
        f32x2 A[32][96];        // 24576 B: fi-row panel, channel-pair float2
        float B[64][96];        // 24576 B: fr-row panel, channel-major scalar
        float sh[3][2][100];    //  2400 B: halo rows for wave-boundary groups
        int   sp;
    } sm;                       // ~51.6 KB -> 3 blocks/CU

    const int t = threadIdx.x;
    const int tu = t >> 4, tv = t & 15;     // 16x16 grid of 6x6 fragments
    const int lane = t & 63;
    const int quad = tu & 3;                // row-subgroup within wave
    const int wv = t >> 6;
    const int u0 = 6 * tu, v0 = 6 * tv;
    const unsigned long long gmask = 0xFFFFull << (lane & 48);

    const int n = blockIdx.x & 1;           // 384 blocks per item, XCD-interleaved

    const float2* fiPn = fiP + (size_t)n * H * (32 * W);
    const float* frPn = frP + (size_t)n * H * (C * W);
    const float* inv = invn + (size_t)n * NP;
    unsigned long long* bn = best + (size_t)n * NP;

    float pA[6][6], pB[6][6];

    for (;;) {
        if (t == 0) sm.sp = (int)atomicAdd(&tick[n * 16], 1u);
        __syncthreads();
        const int uj = sm.sp;               // unit index within item
        if (uj >= UNITS_PER_N) break;

        // ---- decode unit -> (dy, ya, nb), center-out dy order ----
        int dy = 0, ya = 0, nb = 0;
        {
            int r = uj;
            for (int s = 0; s < 187; ++s) {
                int ady = (s + 1) >> 1;          // 0,1,1,2,2,...,93,93
                int nyi = 94 - ady;
                int q = (nyi + PL - 1) / PL;
                if (r < q) {
                    dy = (s & 1) ? -ady : ady;
                    ya = (dy < 0 ? -dy : 0) + r * PL;
                    nb = nyi - r * PL; if (nb > PL) nb = PL;
                    break;
                }
                r -= q;
            }
        }
        const int yb = ya + nb;             // finalize yi in [ya, yb); y runs ya..yb+1

        // prologue: DMA rows (ya, ya+dy)
        stage_row(fiPn + (size_t)ya * (32 * W), &sm.A[0][0], lane, wv);
        stage_row(frPn + (size_t)(ya + dy) * (C * W), &sm.B[0][0], lane, wv);
        asm volatile("s_waitcnt vmcnt(0)" ::: "memory");
        __syncthreads();

        for (int y = ya; y <= yb + 1; ++y) {
            const bool doLd = (y <= yb);
            const bool doFin = (y >= ya + 2);
            const bool doA = (y > ya);
            const int yi = y - 2;
            const int yr = yi + dy;

            // ---- GEMM: q[i][p] accumulates (acc[i][2p], acc[i][2p+1]) ----
            f32x2 q[6][3];
            #pragma unroll
            for (int i = 0; i < 6; ++i)
                #pragma unroll
                for (int p = 0; p < 3; ++p) q[i][p] = (f32x2)(0.f);

            #pragma unroll 2
            for (int c2 = 0; c2 < 32; ++c2) {
                // A fragment for channels (2c2, 2c2+1): 3 aligned b128
                const float4* ap = (const float4*)&sm.A[c2][u0];  // off = 768c2+48tu
                float4 A0 = ap[0], A1 = ap[1], A2 = ap[2];
                // B pixel-pairs for each channel: 3 b64 each
                const f32x2* bpe = (const f32x2*)&sm.B[2 * c2][v0];
                const f32x2* bpo = (const f32x2*)&sm.B[2 * c2 + 1][v0];
                f32x2 be0 = bpe[0], be1 = bpe[1], be2 = bpe[2];
                f32x2 bo0 = bpo[0], bo1 = bpo[1], bo2 = bpo[2];
                // even channel c = 2*c2 (first in ascending-c chain)
                f32x2 s0 = {A0.x, A0.x}, s1 = {A0.z, A0.z}, s2 = {A1.x, A1.x},
                      s3 = {A1.z, A1.z}, s4 = {A2.x, A2.x}, s5 = {A2.z, A2.z};
                VFMA(q[0][0], s0, be0); VFMA(q[0][1], s0, be1); VFMA(q[0][2], s0, be2);
                VFMA(q[1][0], s1, be0); VFMA(q[1][1], s1, be1); VFMA(q[1][2], s1, be2);
                VFMA(q[2][0], s2, be0); VFMA(q[2][1], s2, be1); VFMA(q[2][2], s2, be2);
                VFMA(q[3][0], s3, be0); VFMA(q[3][1], s3, be1); VFMA(q[3][2], s3, be2);
                VFMA(q[4][0], s4, be0); VFMA(q[4][1], s4, be1); VFMA(q[4][2], s4, be2);
                VFMA(q[5][0], s5, be0); VFMA(q[5][1], s5, be1); VFMA(q[5][2], s5, be2);
                // odd channel c = 2*c2+1 (second)
                f32x2 r0 = {A0.y, A0.y}, r1 = {A0.w, A0.w}, r2 = {A1.y, A1.y},
                      r3 = {A1.w, A1.w}, r4 = {A2.y, A2.y}, r5 = {A2.w, A2.w};
                VFMA(q[0][0], r0, bo0); VFMA(q[0][1], r0, bo1); VFMA(q[0][2], r0, bo2);
                VFMA(q[1][0], r1, bo0); VFMA(q[1][1], r1, bo1); VFMA(q[1][2], r1, bo2);
                VFMA(q[2][0], r2, bo0); VFMA(q[2][1], r2, bo1); VFMA(q[2][2], r2, bo2);
                VFMA(q[3][0], r3, bo0); VFMA(q[3][1], r3, bo1); VFMA(q[3][2], r3, bo2);
                VFMA(q[4][0], r4, bo0); VFMA(q[4][1], r4, bo1); VFMA(q[4][2], r4, bo2);
                VFMA(q[5][0], r5, bo0); VFMA(q[5][1], r5, bo1); VFMA(q[5][2], r5, bo2);
            }

            float acc[6][6];
            #pragma unroll
            for (int i = 0; i < 6; ++i)
                #pragma unroll
                for (int jj = 0; jj < 6; ++jj) acc[i][jj] = q[i][jj >> 1][jj & 1];

            // publish halo rows 0,1 for wave-boundary consumers (tu in {3,7,11})
            if (quad == 0 && tu >= 4) {
                const int g = (tu >> 2) - 1;
                #pragma unroll
                for (int jj = 0; jj < 6; ++jj) {
                    sm.sh[g][0][v0 + jj] = acc[0][jj];
                    sm.sh[g][1][v0 + jj] = acc[1][jj];
                }
            }
            __syncthreads();   // barrier1: panel reads done + halo visible

            // issue next-row DMA; latency hides under taps/finalize
            if (doLd) {
                stage_row(fiPn + (size_t)(y + 1) * (32 * W), &sm.A[0][0], lane, wv);
                stage_row(frPn + (size_t)(y + 1 + dy) * (C * W), &sm.B[0][0], lane, wv);
            }

            // ---- neighbor exchange (uniform shfls; select after) ----
            float c6[6], c7[6];
            #pragma unroll
            for (int i = 0; i < 6; ++i) {
                c6[i] = __shfl_down(acc[i][0], 1);   // col u0+i, v0+6
                c7[i] = __shfl_down(acc[i][1], 1);   // col u0+i, v0+7
            }
            float e6[8], e7[8];
            #pragma unroll
            for (int jj = 0; jj < 6; ++jj) {
                e6[jj] = __shfl_down(acc[0][jj], 16);  // row u0+6
                e7[jj] = __shfl_down(acc[1][jj], 16);  // row u0+7
            }
            e6[6] = __shfl_down(acc[0][0], 17);
            e6[7] = __shfl_down(acc[0][1], 17);
            e7[6] = __shfl_down(acc[1][0], 17);
            e7[7] = __shfl_down(acc[1][1], 17);
            if (quad == 3) {
                if (tu < 15) {
                    const int g = tu >> 2;
                    #pragma unroll
                    for (int jj = 0; jj < 8; ++jj) {
                        e6[jj] = sm.sh[g][0][v0 + jj];
                        e7[jj] = sm.sh[g][1][v0 + jj];
                    }
                } else {
                    #pragma unroll
                    for (int jj = 0; jj < 8; ++jj) { e6[jj] = 0.f; e7[jj] = 0.f; }
                }
            }

            float ivr[6];
            if (doFin) {
                const float* ivp = inv + (size_t)yr * HP;
                #pragma unroll
                for (int jj = 0; jj < 6; ++jj) {
                    int xr = v0 + jj;
                    ivr[jj] = ivp[xr > 93 ? 93 : xr];   // clamp; garbage masked later
                }
            }

            // ---- diagonal x-taps + y-rotation + finalize yi = y-2 ----
            #pragma unroll
            for (int i = 0; i < 6; ++i) {
                float bv = -INFINITY; int bxr = 0;
                #pragma unroll
                for (int jj = 0; jj < 6; ++jj) {
                    const int i1 = (i + 1 <= 5) ? i + 1 : 0;
                    const int j1 = (jj + 1 <= 5) ? jj + 1 : 0;
                    const int i2 = (i + 2 <= 5) ? i + 2 : 0;
                    const int j2 = (jj + 2 <= 5) ? jj + 2 : 0;
                    float E0 = acc[i][jj];
                    float E1 = (i + 1 <= 5)
                             ? ((jj + 1 <= 5) ? acc[i1][j1] : c6[i1])
                             : e6[jj + 1];
                    float E2 = (i + 2 <= 5)
                             ? ((jj + 2 <= 5) ? acc[i2][j2]
                                              : ((jj + 2 == 6) ? c6[i2] : c7[i2]))
                             : ((i + 2 == 6) ? e6[jj + 2] : e7[jj + 2]);
                    float bx = (E0 + E1) + E2;           // (g0+g1)+g2, as pass2
                    if (doFin) {
                        float v = (pA[i][jj] + bx) * ivr[jj];  // ((B0+B1)+B2)*inv
                        int xr = v0 + jj;
                        if (xr < HP && (u0 + i) < HP && v > bv) { bv = v; bxr = xr; }
                    }
                    if (doA) pA[i][jj] = pB[i][jj] + bx;
                    pB[i][jj] = bx;
                }
                if (doFin) {
                    float mx = bv;
                    #pragma unroll
                    for (int m = 1; m < 16; m <<= 1)
                        mx = fmaxf(mx, __shfl_xor(mx, m));   // 16-lane xr-group max
                    unsigned long long ball = __ballot(bv == mx) & gmask;
                    int srcl = __ffsll(ball) - 1;            // lowest lane = min xr
                    int wxr = __shfl(bxr, srcl);
                    if (tv == 0 && (u0 + i) < HP) {
                        unsigned long long key =
                            ((unsigned long long)fkey(mx) << 32)
                          | (unsigned int)(~(unsigned int)(yr * HP + wxr));
                        const size_t off = (size_t)yi * HP + (u0 + i);
                        if (key > bn[off]) atomicMax(&bn[off], key);  // monotone: stale-skip safe
                    }
                }
            }

            if (doLd) asm volatile("s_waitcnt vmcnt(0)" ::: "memory");
            __syncthreads();   // barrier2: next panels staged in all quarters
        }
    }
}

// ---------------- Kernel 4: expand to 9 shifted copies, channel-interleaved ----------------
__global__ __launch_bounds__(256) void expand_best_kernel(
    const unsigned long long* __restrict__ best, float* __restrict__ out)
{
    int t = blockIdx.x * 256 + threadIdx.x;
    const int total = NITEM * 18 * HW;
    if (t >= total) return;
    int x = t % W;
    int y = (t / W) % H;
    int chn = (t / HW) % 18;
    int n = t / (18 * HW);
    int k = chn >> 1;
    int b = chn & 1;          // 0 -> flow_h, 1 -> flow_w
    int is = k / 3, js = k - is * 3;
    int ys = y - is, xs = x - js;
    float val = 0.f;
    if (ys >= 0 && ys < HP && xs >= 0 && xs < HP) {
        int i = ys * HP + xs;
        unsigned long long key = best[(size_t)n * NP + i];
        int idx = (int)(~(unsigned int)key);
        int yr = idx / HP, xr = idx - yr * HP;
        val = b ? (float)(xr - xs) : (float)(yr - ys);
    }
    out[t] = val;
}

// ---------------- Launch ----------------
extern "C" void kernel_launch(void* const* d_in, const int* in_sizes, int n_in,
                              void* d_out, int out_size, void* d_ws, size_t ws_size,
                              hipStream_t stream) {
    (void)in_sizes; (void)n_in; (void)out_size; (void)ws_size;
    const float* f1 = (const float*)d_in[0];
    const float* f2 = (const float*)d_in[1];

    float2* fiP = (float2*)d_ws;                            // 2*96*32*96 float2 = 4.7 MB
    float*  frP = (float*)(fiP + (size_t)NITEM * H * 32 * W);  // 4.7 MB
    float*  ssn = frP + (size_t)NITEM * H * C * W;
    float*  invn = ssn + (size_t)NITEM * HW;
    unsigned long long* best =
        (unsigned long long*)((((uintptr_t)(invn + (size_t)NITEM * NP)) + 63) & ~(uintptr_t)63);
    unsigned int* tick = (unsigned int*)(best + (size_t)NITEM * NP);  // 2 pools, 64B apart
    // total ~9.7 MB of workspace

    normalize_kernel<<<(2 * NITEM * HW + 255) / 256, 256, 0, stream>>>(f1, f2, fiP, frP, ssn);
    refnorm_kernel<<<(NITEM * NP + 255) / 256, 256, 0, stream>>>(ssn, invn);
    hipMemsetAsync(best, 0, (size_t)NITEM * NP * sizeof(unsigned long long) + 512, stream);
    corr_fused_kernel<<<NBLOCKS, 256, 0, stream>>>(fiP, frP, invn, best, tick);
    expand_best_kernel<<<(NITEM * 18 * HW + 255) / 256, 256, 0, stream>>>(best, (float*)d_out);
}